// Round 5
// baseline (40128.641 us; speedup 1.0000x reference)
//
#include <hip/hip_runtime.h>

// RNN: h[t] = tanh(W_h h[t-1] + W_x x[t] + b), out = stacked h (fp32).
//
// R5 structure change: 4 CUs per batch element (256 wgs total).
//  - wg (b, s) owns output rows s*128..s*128+127 of batch b.
//  - thread (p = tid>>7, rl = tid&127): partial for row R = s*128+rl over
//    k-groups 16p..16p+15. W for that = 16 uint4 = 64 VGPRs -> fully
//    register-resident (zero W streaming; the R2..R4 bottleneck).
//  - per step: 64 fdot2 -> LDS 4-way k-reduction -> finalizers (tid<128)
//    tanh + write out + write f16 h-slice to global hstage -> release flag
//    (agent scope) -> poll producer flag for needed h slice -> reload h.
//  - blockIdx swizzle co-locates a batch's 4 wgs on one XCD (perf only;
//    correctness uses agent-scope fences -> valid cross-XCD).
//  - hipLaunchCooperativeKernel guarantees all 256 wgs co-resident
//    (spin-sync safe).

typedef _Float16 h2      __attribute__((ext_vector_type(2)));
typedef _Float16 half4_t __attribute__((ext_vector_type(4)));
typedef _Float16 half8_t __attribute__((ext_vector_type(8)));
typedef float    f32x4   __attribute__((ext_vector_type(4)));

#define T_STEPS 1024
#define B_SZ    64
#define NIN     128
#define NH      512
#define WCOLS   641        // NH + NIN + 1

__device__ __forceinline__ float fdot2_(h2 a, h2 b, float c) {
#if __has_builtin(__builtin_amdgcn_fdot2)
    return __builtin_amdgcn_fdot2(a, b, c, false);
#else
    return c + (float)a.x * (float)b.x + (float)a.y * (float)b.y;
#endif
}

__device__ __forceinline__ float dot8(uint4 wu, uint4 hu, float acc) {
    union { uint4 u; h2 h[4]; } w, hv;
    w.u = wu; hv.u = hu;
    acc = fdot2_(w.h[0], hv.h[0], acc);
    acc = fdot2_(w.h[1], hv.h[1], acc);
    acc = fdot2_(w.h[2], hv.h[2], acc);
    acc = fdot2_(w.h[3], hv.h[3], acc);
    return acc;
}

__device__ __forceinline__ float fast_tanh(float x) {
    float z = x * 2.8853900817779268f;        // 2/ln2
#if __has_builtin(__builtin_amdgcn_exp2f)
    float e = __builtin_amdgcn_exp2f(z);
#else
    float e = exp2f(z);
#endif
#if __has_builtin(__builtin_amdgcn_rcpf)
    return 1.f - 2.f * __builtin_amdgcn_rcpf(e + 1.f);
#else
    return 1.f - 2.f / (e + 1.f);
#endif
}

// ---------------- prep: pack W_h f16, pack h0 f16, zero flags ----------------
// Whpk[p*512 + r] = row r, k-group p (8 f16, 16B).
// hstage slot0 [b*64 + j] = h0[b][8j..8j+7] as f16.
__global__ void prep_pack(const float* __restrict__ w_rec,
                          const float* __restrict__ h0,
                          uint4* __restrict__ Whpk,
                          uint4* __restrict__ hstage,
                          int* __restrict__ flags) {
    int o = blockIdx.x * 256 + threadIdx.x;
    if (o < 32768) {
        int r = o & 511, p = o >> 9;
        union { uint4 u; _Float16 f[8]; } pk;
#pragma unroll
        for (int e = 0; e < 8; ++e)
            pk.f[e] = (_Float16)w_rec[r * WCOLS + 8 * p + e];
        Whpk[o] = pk.u;
    } else if (o < 32768 + 4096) {
        int m = o - 32768;                 // b*64 + j
        int bb = m >> 6, j = m & 63;
        union { uint4 u; _Float16 f[8]; } pk;
#pragma unroll
        for (int e = 0; e < 8; ++e)
            pk.f[e] = (_Float16)h0[bb * NH + j * 8 + e];
        hstage[m] = pk.u;                  // slot 0
    } else if (o < 32768 + 4096 + 256) {
        flags[o - 36864] = 0;
    }
}

// ---------------- xin GEMM (f16 MFMA): u = x @ W_x^T + b -> d_out ----------------
// tile M=64 x N=128, K=128. 256 thr = 4 waves; wave w -> cols w*32..w*32+31.
__global__ __launch_bounds__(256) void xin_gemm(const float* __restrict__ x,
                                                const float* __restrict__ w_rec,
                                                float* __restrict__ out) {
    __shared__ _Float16 xs[64][136];    // +8 pad
    __shared__ _Float16 ws[128][136];
    const int tid = threadIdx.x;
    const int m0 = blockIdx.x * 64;
    const int n0 = blockIdx.y * 128;

#pragma unroll
    for (int c = 0; c < 8; ++c) {
        int f = tid + 256 * c;                 // 0..2047
        int row = f >> 5, c4 = (f & 31) * 4;
        float4 v = *(const float4*)(x + (long)(m0 + row) * NIN + c4);
        half4_t hv = {(_Float16)v.x, (_Float16)v.y, (_Float16)v.z, (_Float16)v.w};
        *(half4_t*)&xs[row][c4] = hv;
    }
#pragma unroll
    for (int c = 0; c < 16; ++c) {
        int f = tid + 256 * c;                 // 0..4095
        int row = f >> 5, c4 = (f & 31) * 4;
        const float* src = w_rec + (long)(n0 + row) * WCOLS + NH + c4;
        half4_t hv = {(_Float16)src[0], (_Float16)src[1], (_Float16)src[2], (_Float16)src[3]};
        *(half4_t*)&ws[row][c4] = hv;
    }
    __syncthreads();

    const int lane = tid & 63, w = tid >> 6;
    const int lr = lane & 15, lc = lane >> 4;
    f32x4 acc[4][2];
#pragma unroll
    for (int mi = 0; mi < 4; ++mi)
#pragma unroll
        for (int ni = 0; ni < 2; ++ni) acc[mi][ni] = (f32x4){0.f, 0.f, 0.f, 0.f};

#pragma unroll
    for (int ki = 0; ki < 4; ++ki) {
        int k0 = ki * 32 + lc * 8;
        half8_t a[4], bf[2];
#pragma unroll
        for (int mi = 0; mi < 4; ++mi) a[mi] = *(half8_t*)&xs[mi * 16 + lr][k0];
#pragma unroll
        for (int ni = 0; ni < 2; ++ni) bf[ni] = *(half8_t*)&ws[w * 32 + ni * 16 + lr][k0];
#pragma unroll
        for (int mi = 0; mi < 4; ++mi)
#pragma unroll
            for (int ni = 0; ni < 2; ++ni)
                acc[mi][ni] = __builtin_amdgcn_mfma_f32_16x16x32_f16(
                    a[mi], bf[ni], acc[mi][ni], 0, 0, 0);
    }
    // C/D layout: col=lane&15, row=(lane>>4)*4+reg (m89/m91-verified)
#pragma unroll
    for (int ni = 0; ni < 2; ++ni) {
        int col = n0 + w * 32 + ni * 16 + lr;
        float bv = w_rec[(long)col * WCOLS + NH + NIN];
#pragma unroll
        for (int mi = 0; mi < 4; ++mi)
#pragma unroll
            for (int r = 0; r < 4; ++r) {
                long row = m0 + mi * 16 + lc * 4 + r;
                out[row * NH + col] = acc[mi][ni][r] + bv;
            }
    }
}

// ---------------- serial scan: 4 wgs per batch, flag-synced ----------------
__global__ void __launch_bounds__(512)
__attribute__((amdgpu_waves_per_eu(2, 2)))
rnn_scan(float* __restrict__ out, const uint4* __restrict__ Whpk,
         uint4* __restrict__ hstage, int* __restrict__ flags) {
    __shared__ float part_lds[512];

    const int wgid = blockIdx.x;
    // swizzle: 4 wgs of a batch share XCD (= wgid % 8 under round-robin)
    const int x = wgid & 7;
    const int s = (wgid >> 3) & 3;           // slice: rows s*128..s*128+127
    const int b = x + 8 * (wgid >> 5);       // batch
    const int tid = threadIdx.x;
    const int p  = tid >> 7;                 // k-part: groups 16p..16p+15
    const int rl = tid & 127;
    const int R  = s * 128 + rl;             // this thread's W row

    // W fully register-resident: 16 uint4 = 64 VGPRs
    uint4 Wp[16];
#pragma unroll
    for (int i = 0; i < 16; ++i) Wp[i] = Whpk[(16 * p + i) * NH + R];

    // h_0 from hstage slot 0 (prep-packed)
    const int hbase = b * 64 + 16 * p;       // uint4 index within slot
    uint4 hreg[16];
#pragma unroll
    for (int i = 0; i < 16; ++i) hreg[i] = hstage[hbase + i];

    int* myflag  = &flags[b * 4 + s];        // we produce slice s
    int* srcflag = &flags[b * 4 + p];        // we consume slice p (rows 128p..)

    float u_cur = 0.f;
    if (tid < 128) u_cur = out[b * NH + R];  // u[0]; rl=tid,p=0 here so R=s*128+tid

    for (int t = 0; t < T_STEPS; ++t) {
        float a0 = 0.f, a1 = 0.f, a2 = 0.f, a3 = 0.f;
#pragma unroll
        for (int i = 0; i < 16; i += 4) {
            a0 = dot8(Wp[i],     hreg[i],     a0);
            a1 = dot8(Wp[i + 1], hreg[i + 1], a1);
            a2 = dot8(Wp[i + 2], hreg[i + 2], a2);
            a3 = dot8(Wp[i + 3], hreg[i + 3], a3);
        }
        float u_nxt = 0.f;
        if (tid < 128) {                      // prefetch u[t+1] (clamped)
            long off = (long)((t + 1 < T_STEPS) ? t + 1 : t) * (B_SZ * NH);
            u_nxt = out[off + b * NH + R];
        }
        part_lds[tid] = (a0 + a1) + (a2 + a3);
        __syncthreads();

        if (tid < 128) {
            float v = u_cur + part_lds[tid] + part_lds[128 + tid]
                            + part_lds[256 + tid] + part_lds[384 + tid];
            float hnew = fast_tanh(v);
            out[(long)t * (B_SZ * NH) + b * NH + R] = hnew;
            ((_Float16*)hstage)[((t + 1) & 1) * 32768 + b * NH + R] = (_Float16)hnew;
            u_cur = u_nxt;
        }
        __syncthreads();                      // barrier drains finalizer stores to L2

        if (t + 1 == T_STEPS) break;          // last h never consumed

        if (tid == 0) {
            __threadfence();                  // release: push h stores device-visible
            __hip_atomic_store(myflag, t + 1, __ATOMIC_RELAXED, __HIP_MEMORY_SCOPE_AGENT);
        }
        // wait for producer of our needed h slice (wave-uniform flag)
        while (__hip_atomic_load(srcflag, __ATOMIC_RELAXED, __HIP_MEMORY_SCOPE_AGENT) <= t)
            __builtin_amdgcn_s_sleep(1);
        __threadfence();                      // acquire: invalidate stale cached lines

        const uint4* hsl = hstage + ((t + 1) & 1) * 4096;
#pragma unroll
        for (int i = 0; i < 16; ++i) hreg[i] = hsl[hbase + i];
        __syncthreads();                      // part_lds WAR protection
    }
}

extern "C" void kernel_launch(void* const* d_in, const int* in_sizes, int n_in,
                              void* d_out, int out_size, void* d_ws, size_t ws_size,
                              hipStream_t stream) {
    const float* x     = (const float*)d_in[0];   // (1024,64,128)
    const float* h0    = (const float*)d_in[1];   // (64,512)
    const float* w_rec = (const float*)d_in[2];   // (512,641)
    float* out = (float*)d_out;                   // (1024,64,512)

    // ws: Whpk 512 KiB | hstage 2 slots x 64 KiB | flags 1 KiB
    uint4* Whpk   = (uint4*)d_ws;
    uint4* hstage = Whpk + 32768;
    int*   flags  = (int*)(hstage + 8192);

    prep_pack<<<145, 256, 0, stream>>>(w_rec, h0, Whpk, hstage, flags);

    dim3 gA(T_STEPS * B_SZ / 64, NH / 128);       // 1024 x 4
    xin_gemm<<<gA, 256, 0, stream>>>(x, w_rec, out);

    void* args[] = {(void*)&out, (void*)&Whpk, (void*)&hstage, (void*)&flags};
    hipLaunchCooperativeKernel((const void*)rnn_scan, dim3(256), dim3(512),
                               args, 0, stream);
}